// Round 9
// baseline (341.023 us; speedup 1.0000x reference)
//
#include <hip/hip_runtime.h>
#include <hip/hip_fp16.h>
#include <cstdint>
#include <cstddef>

typedef _Float16 f16;
typedef _Float16 f16x8 __attribute__((ext_vector_type(8)));
typedef _Float16 f16x4 __attribute__((ext_vector_type(4)));
typedef float    f32x4 __attribute__((ext_vector_type(4)));

#define MFMA(a, b, c) __builtin_amdgcn_mfma_f32_16x16x32_f16(a, b, c, 0, 0, 0)

// B=4, S=2048, D=1024, H=16, KS=VS=64, O=1024.

__device__ __forceinline__ void gload_lds16(const f16* g, f16* l) {
    __builtin_amdgcn_global_load_lds(
        (const __attribute__((address_space(1))) void*)g,
        (__attribute__((address_space(3))) void*)l, 16, 0, 0);
}

// ------------------- fp32 -> fp16 convert (Q,K,V fused) ----------------------
__global__ void k_convert3(const float* __restrict__ Q, const float* __restrict__ K,
                           const float* __restrict__ V, f16* __restrict__ Qh,
                           f16* __restrict__ Kh, f16* __restrict__ Vh) {
    const int seg = blockIdx.x >> 11;              // 0..2 (2048 blocks each)
    const int lb  = blockIdx.x & 2047;
    const float* src = seg == 0 ? Q : (seg == 1 ? K : V);
    f16* dst = seg == 0 ? Qh : (seg == 1 ? Kh : Vh);
    int i = lb * blockDim.x + threadIdx.x;
    for (; i < 2097152; i += 524288) {             // n4 = 8192*1024/4
        float4 v = ((const float4*)src)[i];
        f16x4 h;
        h[0] = (f16)v.x; h[1] = (f16)v.y; h[2] = (f16)v.z; h[3] = (f16)v.w;
        ((f16x4*)dst)[i] = h;
    }
}

// ---------------- weight transpose + convert to fp16 (all 4 fused) ----------
// widx 0,1,2: W[H=16][D=1024][KS=64] -> WT + widx*1M, rows n=h*64+ks, cols d
// widx 3:     Wo[K=1024][N=1024]     -> WoT[n][k]
__global__ void k_transpose_all(const float* __restrict__ Wq, const float* __restrict__ Wk,
                                const float* __restrict__ Wv, const float* __restrict__ Wo,
                                f16* __restrict__ WT, f16* __restrict__ WoT) {
    __shared__ float T[64][65];
    const int bx = blockIdx.x;
    const int widx = bx >> 8, sub = bx & 255;
    const int nb = sub >> 4, db = sub & 15;
    const int tid = threadIdx.x;
    const float* W = widx == 0 ? Wq : (widx == 1 ? Wk : (widx == 2 ? Wv : Wo));
    f16* Wt = (widx < 3) ? (WT + (size_t)widx * 1048576) : WoT;
    const float* src = (widx < 3) ? (W + nb * 65536 + db * 4096)
                                  : (W + db * 65536 + nb * 64);
    const int rstride = (widx < 3) ? 64 : 1024;
    {
        int nn = tid & 63, d0 = tid >> 6;
#pragma unroll
        for (int p = 0; p < 16; ++p) {
            int dd = p * 4 + d0;
            T[dd][nn] = src[dd * rstride + nn];
        }
    }
    __syncthreads();
    {
        int dd = tid & 63, n0 = tid >> 6;
#pragma unroll
        for (int p = 0; p < 16; ++p) {
            int nn = p * 4 + n0;
            Wt[(size_t)(nb * 64 + nn) * 1024 + db * 64 + dd] = (f16)T[dd][nn];
        }
    }
}

// --------------------------- fused q/k/v GEMM --------------------------------
// blockIdx.y 0..23: seg = y>>3 (0=q,1=k,2=v), col-block = y&7.
// seg 0: q head-major [(bh)][s][64], scaled by SC
// seg 1: K tile-packed PERMUTED [bh][tile][h=d>>5][p][d&31],
//        p = 16*((ks>>2)&1) + 4*(ks>>3) + (ks&3)
// seg 2: V^T tile-packed [bh][tile=s>>5][vd][s&31]
__global__ __launch_bounds__(256) void k_gemm_qkv(
    const f16* __restrict__ Qh, const f16* __restrict__ Kh, const f16* __restrict__ Vh,
    const f16* __restrict__ WT, const float* __restrict__ bq,
    const float* __restrict__ bk, const float* __restrict__ bv,
    f16* __restrict__ qout, f16* __restrict__ kout, f16* __restrict__ vout, float SC) {
    __shared__ f16 As[128 * 32];
    __shared__ f16 Bs[128 * 32];
    const int yy = blockIdx.y;
    const int seg = yy >> 3;
    const f16* A    = seg == 0 ? Qh : (seg == 1 ? Kh : Vh);
    const f16* Bt   = WT + (size_t)seg * 1048576;
    const float* bias = seg == 0 ? bq : (seg == 1 ? bk : bv);
    const float scale = seg == 0 ? SC : 1.0f;

    const int tid = threadIdx.x;
    const int wid = tid >> 6, lane = tid & 63;
    const int wr = wid >> 1, wc = wid & 1;
    const int lr = lane & 15, lg = lane >> 4;
    const int row0 = blockIdx.x * 128, col0 = (yy & 7) * 128;

    f32x4 acc[4][4];
#pragma unroll
    for (int m = 0; m < 4; ++m)
#pragma unroll
        for (int n = 0; n < 4; ++n) acc[m][n] = (f32x4){0.f, 0.f, 0.f, 0.f};

    const int c0 = tid, c1 = tid + 256;
    const int r0 = c0 >> 2, cb0 = (c0 & 3) * 8;
    const int r1 = c1 >> 2, cb1 = (c1 & 3) * 8;

    for (int k0 = 0; k0 < 1024; k0 += 32) {
        __syncthreads();
        gload_lds16(&A[(size_t)(row0 + r0) * 1024 + k0 + cb0], &As[c0 * 8]);
        gload_lds16(&Bt[(size_t)(col0 + r0) * 1024 + k0 + cb0], &Bs[c0 * 8]);
        gload_lds16(&A[(size_t)(row0 + r1) * 1024 + k0 + cb1], &As[c1 * 8]);
        gload_lds16(&Bt[(size_t)(col0 + r1) * 1024 + k0 + cb1], &Bs[c1 * 8]);
        __syncthreads();
        f16x8 af[4], bf[4];
#pragma unroll
        for (int m = 0; m < 4; ++m) af[m] = *(const f16x8*)&As[(wr * 64 + m * 16 + lr) * 32 + lg * 8];
#pragma unroll
        for (int n = 0; n < 4; ++n) bf[n] = *(const f16x8*)&Bs[(wc * 64 + n * 16 + lr) * 32 + lg * 8];
#pragma unroll
        for (int m = 0; m < 4; ++m)
#pragma unroll
            for (int n = 0; n < 4; ++n) acc[m][n] = MFMA(af[m], bf[n], acc[m][n]);
    }

#pragma unroll
    for (int m = 0; m < 4; ++m) {
#pragma unroll
        for (int n = 0; n < 4; ++n) {
            int col = col0 + wc * 64 + n * 16 + lr;
            float bv_ = bias[col];
            int rowb = row0 + wr * 64 + m * 16 + lg * 4;
            int srow = rowb & 2047;
            if (seg == 0) {
#pragma unroll
                for (int r = 0; r < 4; ++r) {
                    int row = rowb + r;
                    size_t a = ((size_t)((row >> 11) * 16 + (col >> 6)) * 2048 + (row & 2047)) * 64 + (col & 63);
                    qout[a] = (f16)((acc[m][n][r] + bv_) * scale);
                }
            } else if (seg == 1) {
                int ks5 = srow & 31;
                int p0 = ((ks5 >> 2) & 1) * 16 + (ks5 >> 3) * 4 + (ks5 & 3);
                size_t abase = (size_t)((rowb >> 11) * 16 + (col >> 6)) * 131072
                             + (size_t)(srow >> 5) * 2048 + (size_t)((col & 63) >> 5) * 1024
                             + (col & 31);
#pragma unroll
                for (int r = 0; r < 4; ++r)
                    kout[abase + (size_t)(p0 + r) * 32] = (f16)(acc[m][n][r] + bv_);
            } else {
                size_t a = (size_t)((rowb >> 11) * 16 + (col >> 6)) * 131072
                         + (size_t)(srow >> 5) * 2048 + (size_t)(col & 63) * 32 + (srow & 31);
                f16x4 ov;
#pragma unroll
                for (int r = 0; r < 4; ++r) ov[r] = (f16)(acc[m][n][r] + bv_);
                *(f16x4*)&vout[a] = ov;
            }
        }
    }
}

// ------------------------------ output GEMM ----------------------------------
__global__ __launch_bounds__(256) void k_gemm_out(const f16* __restrict__ A,
                                                  const f16* __restrict__ Bt,
                                                  const float* __restrict__ bias,
                                                  float* __restrict__ Cout) {
    __shared__ f16 As[128 * 32];
    __shared__ f16 Bs[128 * 32];
    const int tid = threadIdx.x;
    const int wid = tid >> 6, lane = tid & 63;
    const int wr = wid >> 1, wc = wid & 1;
    const int lr = lane & 15, lg = lane >> 4;
    const int row0 = blockIdx.x * 128, col0 = blockIdx.y * 128;

    f32x4 acc[4][4];
#pragma unroll
    for (int m = 0; m < 4; ++m)
#pragma unroll
        for (int n = 0; n < 4; ++n) acc[m][n] = (f32x4){0.f, 0.f, 0.f, 0.f};

    const int c0 = tid, c1 = tid + 256;
    const int r0 = c0 >> 2, cb0 = (c0 & 3) * 8;
    const int r1 = c1 >> 2, cb1 = (c1 & 3) * 8;

    for (int k0 = 0; k0 < 1024; k0 += 32) {
        __syncthreads();
        gload_lds16(&A[(size_t)(row0 + r0) * 1024 + k0 + cb0], &As[c0 * 8]);
        gload_lds16(&Bt[(size_t)(col0 + r0) * 1024 + k0 + cb0], &Bs[c0 * 8]);
        gload_lds16(&A[(size_t)(row0 + r1) * 1024 + k0 + cb1], &As[c1 * 8]);
        gload_lds16(&Bt[(size_t)(col0 + r1) * 1024 + k0 + cb1], &Bs[c1 * 8]);
        __syncthreads();
        f16x8 af[4], bf[4];
#pragma unroll
        for (int m = 0; m < 4; ++m) af[m] = *(const f16x8*)&As[(wr * 64 + m * 16 + lr) * 32 + lg * 8];
#pragma unroll
        for (int n = 0; n < 4; ++n) bf[n] = *(const f16x8*)&Bs[(wc * 64 + n * 16 + lr) * 32 + lg * 8];
#pragma unroll
        for (int m = 0; m < 4; ++m)
#pragma unroll
            for (int n = 0; n < 4; ++n) acc[m][n] = MFMA(af[m], bf[n], acc[m][n]);
    }

#pragma unroll
    for (int m = 0; m < 4; ++m) {
#pragma unroll
        for (int n = 0; n < 4; ++n) {
            int col = col0 + wc * 64 + n * 16 + lr;
            float bv = bias[col];
#pragma unroll
            for (int r = 0; r < 4; ++r) {
                int row = row0 + wr * 64 + m * 16 + lg * 4 + r;
                Cout[(size_t)row * 1024 + col] = acc[m][n][r] + bv;
            }
        }
    }
}

// ------------------------------ attention -----------------------------------
// No LDS. 1024 blocks (XCD-swizzled), 4 waves/block, 32 q-rows/wave.
// Tile-packed permuted K/V (contiguous 1KB wave loads; S^T lands in PV B-frag
// layout; l via ones-row MFMA; lazy max; exp2/cvt_pkrtz).
// NEW: 1-tile software pipeline (T15 analog): body computes QK^T(t), then
// PV(t-1) (pure-MFMA, independent of st(t)), then softmax(t). The PV MFMA
// cluster and the softmax VALU/TRANS stream have no data dependence, so
// in-order issue keeps matrix + VALU pipes concurrently fed inside one wave.
// Manual 2x unroll with named vvA/vvB, pfA/pfB register sets (static idx).
__global__ __launch_bounds__(256, 4) void k_attn(const f16* __restrict__ q,
                                                 const f16* __restrict__ k2,
                                                 const f16* __restrict__ v2,
                                                 f16* __restrict__ cat) {
    const int g = blockIdx.x;
    const int xcd = g & 7, i = g >> 3;
    const int bh = xcd + 8 * (i >> 4);        // bijective, 64 values
    const int qb = i & 15;
    const int b = bh >> 4, h = bh & 15;

    const int tid = threadIdx.x, wid = tid >> 6, lane = tid & 63;
    const int lr = lane & 15, lg = lane >> 4;
    const int qw = qb * 128 + wid * 32;

    const float THR = 8.0f;

    f16x8 qf[2][2];
#pragma unroll
    for (int qt = 0; qt < 2; ++qt)
#pragma unroll
        for (int hf = 0; hf < 2; ++hf)
            qf[qt][hf] = *(const f16x8*)&q[((size_t)bh * 2048 + qw + qt * 16 + lr) * 64 + hf * 32 + lg * 8];

    const f16* kbase = k2 + (size_t)bh * 131072 + lr * 32 + lg * 8;
    const f16* vbase = v2 + (size_t)bh * 131072 + lr * 32 + lg * 8;

    f32x4 o[2][4], ol[2];
#pragma unroll
    for (int qt = 0; qt < 2; ++qt) {
#pragma unroll
        for (int m = 0; m < 4; ++m) o[qt][m] = (f32x4){0.f, 0.f, 0.f, 0.f};
        ol[qt] = (f32x4){0.f, 0.f, 0.f, 0.f};
    }
    float m_r[2] = {-1.0e30f, -1.0e30f};

    f16x8 ones;
#pragma unroll
    for (int j = 0; j < 8; ++j) ones[j] = (f16)1.0f;

    f16x8 ka[4], vvA[4], vvB[4];
    f16x8 pfA[2], pfB[2];
    f32x4 st[2][2];

    auto loadK = [&](int t) {
        const f16* kn = kbase + (size_t)t * 2048;
        ka[0] = *(const f16x8*)(kn);
        ka[1] = *(const f16x8*)(kn + 1024);
        ka[2] = *(const f16x8*)(kn + 512);
        ka[3] = *(const f16x8*)(kn + 1536);
    };
    auto loadV = [&](f16x8* vv, int t) {
        const f16* vt = vbase + (size_t)t * 2048;
        vv[0] = *(const f16x8*)(vt);
        vv[1] = *(const f16x8*)(vt + 512);
        vv[2] = *(const f16x8*)(vt + 1024);
        vv[3] = *(const f16x8*)(vt + 1536);
    };
    auto qkt = [&]() {
        __builtin_amdgcn_s_setprio(1);
#pragma unroll
        for (int t = 0; t < 2; ++t)
#pragma unroll
            for (int qt = 0; qt < 2; ++qt) {
                f32x4 z = (f32x4){0.f, 0.f, 0.f, 0.f};
                z = MFMA(ka[t * 2 + 0], qf[qt][0], z);
                z = MFMA(ka[t * 2 + 1], qf[qt][1], z);
                st[qt][t] = z;
            }
        __builtin_amdgcn_s_setprio(0);
    };
    auto pv = [&](const f16x8* vv, const f16x8* pf) {
        __builtin_amdgcn_s_setprio(1);
#pragma unroll
        for (int qt = 0; qt < 2; ++qt) {
            o[qt][0] = MFMA(vv[0], pf[qt], o[qt][0]);
            o[qt][1] = MFMA(vv[1], pf[qt], o[qt][1]);
            o[qt][2] = MFMA(vv[2], pf[qt], o[qt][2]);
            o[qt][3] = MFMA(vv[3], pf[qt], o[qt][3]);
            ol[qt]   = MFMA(ones, pf[qt], ol[qt]);
        }
        __builtin_amdgcn_s_setprio(0);
    };
    auto softmax_step = [&](f16x8* pf) {
        float lm[2];
#pragma unroll
        for (int qt = 0; qt < 2; ++qt) {
            float a0 = fmaxf(fmaxf(st[qt][0][0], st[qt][0][1]), st[qt][0][2]);
            float b0 = fmaxf(fmaxf(st[qt][0][3], st[qt][1][0]), st[qt][1][1]);
            float c0 = fmaxf(fmaxf(st[qt][1][2], st[qt][1][3]), a0);
            lm[qt] = fmaxf(b0, c0);
        }
        if (__any((lm[0] > m_r[0] + THR) || (lm[1] > m_r[1] + THR))) {
#pragma unroll
            for (int qt = 0; qt < 2; ++qt) {
                float t0 = lm[qt];
                t0 = fmaxf(t0, __shfl_xor(t0, 16, 64));
                t0 = fmaxf(t0, __shfl_xor(t0, 32, 64));
                float m_new = fmaxf(m_r[qt], t0);
                float alpha = __builtin_amdgcn_exp2f(m_r[qt] - m_new);
#pragma unroll
                for (int m = 0; m < 4; ++m)
#pragma unroll
                    for (int r = 0; r < 4; ++r) o[qt][m][r] *= alpha;
#pragma unroll
                for (int r = 0; r < 4; ++r) ol[qt][r] *= alpha;
                m_r[qt] = m_new;
            }
        }
#pragma unroll
        for (int qt = 0; qt < 2; ++qt) {
            union { uint32_t u[4]; f16x8 v; } bb;
#pragma unroll
            for (int t = 0; t < 2; ++t)
#pragma unroll
                for (int pr = 0; pr < 2; ++pr) {
                    float e0 = __builtin_amdgcn_exp2f(st[qt][t][2 * pr] - m_r[qt]);
                    float e1 = __builtin_amdgcn_exp2f(st[qt][t][2 * pr + 1] - m_r[qt]);
                    auto hp = __builtin_amdgcn_cvt_pkrtz(e0, e1);
                    bb.u[t * 2 + pr] = __builtin_bit_cast(uint32_t, hp);
                }
            pf[qt] = bb.v;
        }
    };

    // ---- prologue: tile 0 ----
    loadK(0);
    loadV(vvA, 0);
    qkt();                 // QK^T(0)
    loadK(1);
    softmax_step(pfA);     // P(0) (first-tile rescale always triggers; o=0)

    // ---- pipelined main loop: tiles 1..62, two per iteration ----
    for (int it = 0; it < 31; ++it) {
        const int t1 = 2 * it + 1, t2 = 2 * it + 2;
        qkt();                     // QK^T(t1) from ka=K(t1)
        loadK(t1 + 1);
        loadV(vvB, t1);
        pv(vvA, pfA);              // PV(t1-1)  [MFMA ∥ softmax below]
        softmax_step(pfB);         // P(t1)

        qkt();                     // QK^T(t2) from ka=K(t2)
        loadK(t2 + 1);
        loadV(vvA, t2);
        pv(vvB, pfB);              // PV(t2-1)
        softmax_step(pfA);         // P(t2)
    }

    // ---- epilogue: tile 63 ----
    qkt();                         // QK^T(63) from ka=K(63)
    loadV(vvB, 63);
    pv(vvA, pfA);                  // PV(62)
    softmax_step(pfB);             // P(63)
    pv(vvB, pfB);                  // PV(63)

    // normalize + store (l lane-local via ones-MFMA)
#pragma unroll
    for (int qt = 0; qt < 2; ++qt) {
        float inv = 1.f / ol[qt][0];
        size_t cb = ((size_t)b * 2048 + qw + qt * 16 + lr) * 1024 + h * 64 + lg * 4;
#pragma unroll
        for (int m = 0; m < 4; ++m) {
            f16x4 ov;
#pragma unroll
            for (int r = 0; r < 4; ++r) ov[r] = (f16)(o[qt][m][r] * inv);
            *(f16x4*)&cat[cb + m * 16] = ov;
        }
    }
}

// ---------------------------------------------------------------------------
extern "C" void kernel_launch(void* const* d_in, const int* in_sizes, int n_in,
                              void* d_out, int out_size, void* d_ws, size_t ws_size,
                              hipStream_t stream) {
    const float* Q  = (const float*)d_in[0];
    const float* K  = (const float*)d_in[1];
    const float* V  = (const float*)d_in[2];
    const float* Wq = (const float*)d_in[3];
    const float* bq = (const float*)d_in[4];
    const float* Wk = (const float*)d_in[5];
    const float* bk = (const float*)d_in[6];
    const float* Wv = (const float*)d_in[7];
    const float* bv = (const float*)d_in[8];
    const float* Wo = (const float*)d_in[9];
    const float* bo = (const float*)d_in[10];

    char* ws = (char*)d_ws;
    size_t off = 0;
    auto alloc = [&](size_t bytes) {
        char* p = ws + off;
        off += (bytes + 255) & ~(size_t)255;
        return p;
    };
    f16* Qh  = (f16*)alloc(8192ULL * 1024 * 2);
    f16* Kh  = (f16*)alloc(8192ULL * 1024 * 2);
    f16* Vh  = (f16*)alloc(8192ULL * 1024 * 2);
    f16* WT  = (f16*)alloc(3ULL * 1024 * 1024 * 2);   // WqT|WkT|WvT contiguous
    f16* WoT = (f16*)alloc(1024ULL * 1024 * 2);
    f16* qb  = (f16*)alloc(8192ULL * 1024 * 2);   // head-major [(b,h)][s][64]
    f16* kb2 = (f16*)alloc(8192ULL * 1024 * 2);   // [bh][tile][h][p][32] permuted
    f16* vb2 = (f16*)alloc(8192ULL * 1024 * 2);   // [bh][tile][vd][32]
    f16* cat = (f16*)alloc(8192ULL * 1024 * 2);   // [B*S][H*VS]

    k_convert3<<<6144, 256, 0, stream>>>(Q, K, V, Qh, Kh, Vh);
    k_transpose_all<<<1024, 256, 0, stream>>>(Wq, Wk, Wv, Wo, WT, WoT);

    const float SC = 0.125f * 1.44269504089f;   // 1/sqrt(64) * log2(e), folded into q
    k_gemm_qkv<<<dim3(64, 24), 256, 0, stream>>>(Qh, Kh, Vh, WT, bq, bk, bv,
                                                 qb, kb2, vb2, SC);

    k_attn<<<1024, 256, 0, stream>>>(qb, kb2, vb2, cat);

    k_gemm_out<<<dim3(64, 8), 256, 0, stream>>>(cat, WoT, bo, (float*)d_out);
}

// Round 10
// 242.896 us; speedup vs baseline: 1.4040x; 1.4040x over previous
//
#include <hip/hip_runtime.h>
#include <hip/hip_fp16.h>
#include <cstdint>
#include <cstddef>

typedef _Float16 f16;
typedef _Float16 f16x8 __attribute__((ext_vector_type(8)));
typedef _Float16 f16x4 __attribute__((ext_vector_type(4)));
typedef float    f32x4 __attribute__((ext_vector_type(4)));

#define MFMA(a, b, c) __builtin_amdgcn_mfma_f32_16x16x32_f16(a, b, c, 0, 0, 0)

// B=4, S=2048, D=1024, H=16, KS=VS=64, O=1024.

__device__ __forceinline__ void gload_lds16(const f16* g, f16* l) {
    __builtin_amdgcn_global_load_lds(
        (const __attribute__((address_space(1))) void*)g,
        (__attribute__((address_space(3))) void*)l, 16, 0, 0);
}

// ------------------- fp32 -> fp16 convert (Q,K,V fused) ----------------------
__global__ void k_convert3(const float* __restrict__ Q, const float* __restrict__ K,
                           const float* __restrict__ V, f16* __restrict__ Qh,
                           f16* __restrict__ Kh, f16* __restrict__ Vh) {
    const int seg = blockIdx.x >> 11;              // 0..2 (2048 blocks each)
    const int lb  = blockIdx.x & 2047;
    const float* src = seg == 0 ? Q : (seg == 1 ? K : V);
    f16* dst = seg == 0 ? Qh : (seg == 1 ? Kh : Vh);
    int i = lb * blockDim.x + threadIdx.x;
    for (; i < 2097152; i += 524288) {             // n4 = 8192*1024/4
        float4 v = ((const float4*)src)[i];
        f16x4 h;
        h[0] = (f16)v.x; h[1] = (f16)v.y; h[2] = (f16)v.z; h[3] = (f16)v.w;
        ((f16x4*)dst)[i] = h;
    }
}

// ---------------- weight transpose + convert to fp16 (all 4 fused) ----------
// widx 0,1,2: W[H=16][D=1024][KS=64] -> WT + widx*1M, rows n=h*64+ks, cols d
// widx 3:     Wo[K=1024][N=1024]     -> WoT[n][k]
__global__ void k_transpose_all(const float* __restrict__ Wq, const float* __restrict__ Wk,
                                const float* __restrict__ Wv, const float* __restrict__ Wo,
                                f16* __restrict__ WT, f16* __restrict__ WoT) {
    __shared__ float T[64][65];
    const int bx = blockIdx.x;
    const int widx = bx >> 8, sub = bx & 255;
    const int nb = sub >> 4, db = sub & 15;
    const int tid = threadIdx.x;
    const float* W = widx == 0 ? Wq : (widx == 1 ? Wk : (widx == 2 ? Wv : Wo));
    f16* Wt = (widx < 3) ? (WT + (size_t)widx * 1048576) : WoT;
    const float* src = (widx < 3) ? (W + nb * 65536 + db * 4096)
                                  : (W + db * 65536 + nb * 64);
    const int rstride = (widx < 3) ? 64 : 1024;
    {
        int nn = tid & 63, d0 = tid >> 6;
#pragma unroll
        for (int p = 0; p < 16; ++p) {
            int dd = p * 4 + d0;
            T[dd][nn] = src[dd * rstride + nn];
        }
    }
    __syncthreads();
    {
        int dd = tid & 63, n0 = tid >> 6;
#pragma unroll
        for (int p = 0; p < 16; ++p) {
            int nn = p * 4 + n0;
            Wt[(size_t)(nb * 64 + nn) * 1024 + db * 64 + dd] = (f16)T[dd][nn];
        }
    }
}

// --------------------------- fused q/k/v GEMM --------------------------------
// blockIdx.y 0..23: seg = y>>3 (0=q,1=k,2=v), col-block = y&7.
// seg 0: q head-major [(bh)][s][64], scaled by SC
// seg 1: K tile-packed PERMUTED [bh][tile][h=d>>5][p][d&31],
//        p = 16*((ks>>2)&1) + 4*(ks>>3) + (ks&3)
// seg 2: V^T tile-packed [bh][tile=s>>5][vd][s&31]
__global__ __launch_bounds__(256) void k_gemm_qkv(
    const f16* __restrict__ Qh, const f16* __restrict__ Kh, const f16* __restrict__ Vh,
    const f16* __restrict__ WT, const float* __restrict__ bq,
    const float* __restrict__ bk, const float* __restrict__ bv,
    f16* __restrict__ qout, f16* __restrict__ kout, f16* __restrict__ vout, float SC) {
    __shared__ f16 As[128 * 32];
    __shared__ f16 Bs[128 * 32];
    const int yy = blockIdx.y;
    const int seg = yy >> 3;
    const f16* A    = seg == 0 ? Qh : (seg == 1 ? Kh : Vh);
    const f16* Bt   = WT + (size_t)seg * 1048576;
    const float* bias = seg == 0 ? bq : (seg == 1 ? bk : bv);
    const float scale = seg == 0 ? SC : 1.0f;

    const int tid = threadIdx.x;
    const int wid = tid >> 6, lane = tid & 63;
    const int wr = wid >> 1, wc = wid & 1;
    const int lr = lane & 15, lg = lane >> 4;
    const int row0 = blockIdx.x * 128, col0 = (yy & 7) * 128;

    f32x4 acc[4][4];
#pragma unroll
    for (int m = 0; m < 4; ++m)
#pragma unroll
        for (int n = 0; n < 4; ++n) acc[m][n] = (f32x4){0.f, 0.f, 0.f, 0.f};

    const int c0 = tid, c1 = tid + 256;
    const int r0 = c0 >> 2, cb0 = (c0 & 3) * 8;
    const int r1 = c1 >> 2, cb1 = (c1 & 3) * 8;

    for (int k0 = 0; k0 < 1024; k0 += 32) {
        __syncthreads();
        gload_lds16(&A[(size_t)(row0 + r0) * 1024 + k0 + cb0], &As[c0 * 8]);
        gload_lds16(&Bt[(size_t)(col0 + r0) * 1024 + k0 + cb0], &Bs[c0 * 8]);
        gload_lds16(&A[(size_t)(row0 + r1) * 1024 + k0 + cb1], &As[c1 * 8]);
        gload_lds16(&Bt[(size_t)(col0 + r1) * 1024 + k0 + cb1], &Bs[c1 * 8]);
        __syncthreads();
        f16x8 af[4], bf[4];
#pragma unroll
        for (int m = 0; m < 4; ++m) af[m] = *(const f16x8*)&As[(wr * 64 + m * 16 + lr) * 32 + lg * 8];
#pragma unroll
        for (int n = 0; n < 4; ++n) bf[n] = *(const f16x8*)&Bs[(wc * 64 + n * 16 + lr) * 32 + lg * 8];
#pragma unroll
        for (int m = 0; m < 4; ++m)
#pragma unroll
            for (int n = 0; n < 4; ++n) acc[m][n] = MFMA(af[m], bf[n], acc[m][n]);
    }

#pragma unroll
    for (int m = 0; m < 4; ++m) {
#pragma unroll
        for (int n = 0; n < 4; ++n) {
            int col = col0 + wc * 64 + n * 16 + lr;
            float bv_ = bias[col];
            int rowb = row0 + wr * 64 + m * 16 + lg * 4;
            int srow = rowb & 2047;
            if (seg == 0) {
#pragma unroll
                for (int r = 0; r < 4; ++r) {
                    int row = rowb + r;
                    size_t a = ((size_t)((row >> 11) * 16 + (col >> 6)) * 2048 + (row & 2047)) * 64 + (col & 63);
                    qout[a] = (f16)((acc[m][n][r] + bv_) * scale);
                }
            } else if (seg == 1) {
                int ks5 = srow & 31;
                int p0 = ((ks5 >> 2) & 1) * 16 + (ks5 >> 3) * 4 + (ks5 & 3);
                size_t abase = (size_t)((rowb >> 11) * 16 + (col >> 6)) * 131072
                             + (size_t)(srow >> 5) * 2048 + (size_t)((col & 63) >> 5) * 1024
                             + (col & 31);
#pragma unroll
                for (int r = 0; r < 4; ++r)
                    kout[abase + (size_t)(p0 + r) * 32] = (f16)(acc[m][n][r] + bv_);
            } else {
                size_t a = (size_t)((rowb >> 11) * 16 + (col >> 6)) * 131072
                         + (size_t)(srow >> 5) * 2048 + (size_t)(col & 63) * 32 + (srow & 31);
                f16x4 ov;
#pragma unroll
                for (int r = 0; r < 4; ++r) ov[r] = (f16)(acc[m][n][r] + bv_);
                *(f16x4*)&vout[a] = ov;
            }
        }
    }
}

// ------------------------------ output GEMM ----------------------------------
__global__ __launch_bounds__(256) void k_gemm_out(const f16* __restrict__ A,
                                                  const f16* __restrict__ Bt,
                                                  const float* __restrict__ bias,
                                                  float* __restrict__ Cout) {
    __shared__ f16 As[128 * 32];
    __shared__ f16 Bs[128 * 32];
    const int tid = threadIdx.x;
    const int wid = tid >> 6, lane = tid & 63;
    const int wr = wid >> 1, wc = wid & 1;
    const int lr = lane & 15, lg = lane >> 4;
    const int row0 = blockIdx.x * 128, col0 = blockIdx.y * 128;

    f32x4 acc[4][4];
#pragma unroll
    for (int m = 0; m < 4; ++m)
#pragma unroll
        for (int n = 0; n < 4; ++n) acc[m][n] = (f32x4){0.f, 0.f, 0.f, 0.f};

    const int c0 = tid, c1 = tid + 256;
    const int r0 = c0 >> 2, cb0 = (c0 & 3) * 8;
    const int r1 = c1 >> 2, cb1 = (c1 & 3) * 8;

    for (int k0 = 0; k0 < 1024; k0 += 32) {
        __syncthreads();
        gload_lds16(&A[(size_t)(row0 + r0) * 1024 + k0 + cb0], &As[c0 * 8]);
        gload_lds16(&Bt[(size_t)(col0 + r0) * 1024 + k0 + cb0], &Bs[c0 * 8]);
        gload_lds16(&A[(size_t)(row0 + r1) * 1024 + k0 + cb1], &As[c1 * 8]);
        gload_lds16(&Bt[(size_t)(col0 + r1) * 1024 + k0 + cb1], &Bs[c1 * 8]);
        __syncthreads();
        f16x8 af[4], bf[4];
#pragma unroll
        for (int m = 0; m < 4; ++m) af[m] = *(const f16x8*)&As[(wr * 64 + m * 16 + lr) * 32 + lg * 8];
#pragma unroll
        for (int n = 0; n < 4; ++n) bf[n] = *(const f16x8*)&Bs[(wc * 64 + n * 16 + lr) * 32 + lg * 8];
#pragma unroll
        for (int m = 0; m < 4; ++m)
#pragma unroll
            for (int n = 0; n < 4; ++n) acc[m][n] = MFMA(af[m], bf[n], acc[m][n]);
    }

#pragma unroll
    for (int m = 0; m < 4; ++m) {
#pragma unroll
        for (int n = 0; n < 4; ++n) {
            int col = col0 + wc * 64 + n * 16 + lr;
            float bv = bias[col];
#pragma unroll
            for (int r = 0; r < 4; ++r) {
                int row = row0 + wr * 64 + m * 16 + lg * 4 + r;
                Cout[(size_t)row * 1024 + col] = acc[m][n][r] + bv;
            }
        }
    }
}

// ------------------------------ attention -----------------------------------
// No LDS. 1024 blocks (XCD-swizzled), 4 waves/block, 32 q-rows/wave.
// Tile-packed permuted K/V (contiguous 1KB wave loads; S^T lands in PV B-frag
// layout). FLAT single-buffer software pipeline (round-9 lesson: NO lambdas /
// pointer-passed register arrays — they spill to scratch). Body order:
//   qkt(t) -> loadK(t+1) -> PV(t-1) -> softmax(t)->pf -> loadV(t)->vv
// PV (pure MFMA, uses prev-tile pf/vv) issues before the st-dependent softmax
// VALU stream, so matrix + VALU pipes run concurrently inside one wave, with
// only ONE pf/vv register set live (~116 VGPR, under the (256,4) 128 cap).
// l = per-lane partial sums, reduced once in the epilogue.
__global__ __launch_bounds__(256, 4) void k_attn(const f16* __restrict__ q,
                                                 const f16* __restrict__ k2,
                                                 const f16* __restrict__ v2,
                                                 f16* __restrict__ cat) {
    const int g = blockIdx.x;
    const int xcd = g & 7, i = g >> 3;
    const int bh = xcd + 8 * (i >> 4);        // bijective, 64 values
    const int qb = i & 15;
    const int b = bh >> 4, h = bh & 15;

    const int tid = threadIdx.x, wid = tid >> 6, lane = tid & 63;
    const int lr = lane & 15, lg = lane >> 4;
    const int qw = qb * 128 + wid * 32;

    const float THR = 8.0f;

    f16x8 qf[2][2];
#pragma unroll
    for (int qt = 0; qt < 2; ++qt)
#pragma unroll
        for (int hf = 0; hf < 2; ++hf)
            qf[qt][hf] = *(const f16x8*)&q[((size_t)bh * 2048 + qw + qt * 16 + lr) * 64 + hf * 32 + lg * 8];

    const f16* kp = k2 + (size_t)bh * 131072 + lr * 32 + lg * 8;
    const f16* vp = v2 + (size_t)bh * 131072 + lr * 32 + lg * 8;

    f32x4 o[2][4];
#pragma unroll
    for (int qt = 0; qt < 2; ++qt)
#pragma unroll
        for (int m = 0; m < 4; ++m) o[qt][m] = (f32x4){0.f, 0.f, 0.f, 0.f};
    float m_r[2] = {-1.0e30f, -1.0e30f}, l_p[2] = {0.f, 0.f};

    f16x8 ka[4], vv[4], pf[2];
    f32x4 st[2][2];

    // ---- prologue: tile 0 ----
    ka[0] = *(const f16x8*)(kp);
    ka[1] = *(const f16x8*)(kp + 1024);
    ka[2] = *(const f16x8*)(kp + 512);
    ka[3] = *(const f16x8*)(kp + 1536);
    kp += 2048;

    // QK^T(0)
    __builtin_amdgcn_s_setprio(1);
#pragma unroll
    for (int t = 0; t < 2; ++t)
#pragma unroll
        for (int qt = 0; qt < 2; ++qt) {
            f32x4 z = (f32x4){0.f, 0.f, 0.f, 0.f};
            z = MFMA(ka[t * 2 + 0], qf[qt][0], z);
            z = MFMA(ka[t * 2 + 1], qf[qt][1], z);
            st[qt][t] = z;
        }
    __builtin_amdgcn_s_setprio(0);

    // load K(1)
    ka[0] = *(const f16x8*)(kp);
    ka[1] = *(const f16x8*)(kp + 1024);
    ka[2] = *(const f16x8*)(kp + 512);
    ka[3] = *(const f16x8*)(kp + 1536);
    kp += 2048;

    // softmax(0) -> pf  (first tile: rescale always triggers, o==0)
    {
        float lm[2];
#pragma unroll
        for (int qt = 0; qt < 2; ++qt) {
            float a0 = fmaxf(fmaxf(st[qt][0][0], st[qt][0][1]), st[qt][0][2]);
            float b0 = fmaxf(fmaxf(st[qt][0][3], st[qt][1][0]), st[qt][1][1]);
            float c0 = fmaxf(fmaxf(st[qt][1][2], st[qt][1][3]), a0);
            lm[qt] = fmaxf(b0, c0);
            float t0 = lm[qt];
            t0 = fmaxf(t0, __shfl_xor(t0, 16, 64));
            t0 = fmaxf(t0, __shfl_xor(t0, 32, 64));
            m_r[qt] = t0;
        }
#pragma unroll
        for (int qt = 0; qt < 2; ++qt) {
            float ps = 0.f;
            union { uint32_t u[4]; f16x8 v; } bb;
#pragma unroll
            for (int t = 0; t < 2; ++t)
#pragma unroll
                for (int pr = 0; pr < 2; ++pr) {
                    float e0 = __builtin_amdgcn_exp2f(st[qt][t][2 * pr] - m_r[qt]);
                    float e1 = __builtin_amdgcn_exp2f(st[qt][t][2 * pr + 1] - m_r[qt]);
                    ps += e0 + e1;
                    auto hp = __builtin_amdgcn_cvt_pkrtz(e0, e1);
                    bb.u[t * 2 + pr] = __builtin_bit_cast(uint32_t, hp);
                }
            l_p[qt] += ps;
            pf[qt] = bb.v;
        }
    }

    // load V(0)
    vv[0] = *(const f16x8*)(vp);
    vv[1] = *(const f16x8*)(vp + 512);
    vv[2] = *(const f16x8*)(vp + 1024);
    vv[3] = *(const f16x8*)(vp + 1536);
    vp += 2048;

    // ---- main loop: tiles 1..63 ----
    for (int tt = 1; tt < 64; ++tt) {
        // QK^T(tt) from ka = K(tt)
        __builtin_amdgcn_s_setprio(1);
#pragma unroll
        for (int t = 0; t < 2; ++t)
#pragma unroll
            for (int qt = 0; qt < 2; ++qt) {
                f32x4 z = (f32x4){0.f, 0.f, 0.f, 0.f};
                z = MFMA(ka[t * 2 + 0], qf[qt][0], z);
                z = MFMA(ka[t * 2 + 1], qf[qt][1], z);
                st[qt][t] = z;
            }
        __builtin_amdgcn_s_setprio(0);

        // prefetch K(tt+1)  (tt=63 reads one tile past kb2 -> start of vb2, in-bounds)
        ka[0] = *(const f16x8*)(kp);
        ka[1] = *(const f16x8*)(kp + 1024);
        ka[2] = *(const f16x8*)(kp + 512);
        ka[3] = *(const f16x8*)(kp + 1536);
        kp += 2048;

        // PV(tt-1): pure MFMA on prev pf/vv — issues ahead of the softmax VALU
        __builtin_amdgcn_s_setprio(1);
#pragma unroll
        for (int qt = 0; qt < 2; ++qt) {
            o[qt][0] = MFMA(vv[0], pf[qt], o[qt][0]);
            o[qt][1] = MFMA(vv[1], pf[qt], o[qt][1]);
            o[qt][2] = MFMA(vv[2], pf[qt], o[qt][2]);
            o[qt][3] = MFMA(vv[3], pf[qt], o[qt][3]);
        }
        __builtin_amdgcn_s_setprio(0);

        // softmax(tt): lazy max + P pack (overwrites pf)
        {
            float lm[2];
#pragma unroll
            for (int qt = 0; qt < 2; ++qt) {
                float a0 = fmaxf(fmaxf(st[qt][0][0], st[qt][0][1]), st[qt][0][2]);
                float b0 = fmaxf(fmaxf(st[qt][0][3], st[qt][1][0]), st[qt][1][1]);
                float c0 = fmaxf(fmaxf(st[qt][1][2], st[qt][1][3]), a0);
                lm[qt] = fmaxf(b0, c0);
            }
            if (__any((lm[0] > m_r[0] + THR) || (lm[1] > m_r[1] + THR))) {
#pragma unroll
                for (int qt = 0; qt < 2; ++qt) {
                    float t0 = lm[qt];
                    t0 = fmaxf(t0, __shfl_xor(t0, 16, 64));
                    t0 = fmaxf(t0, __shfl_xor(t0, 32, 64));
                    float m_new = fmaxf(m_r[qt], t0);
                    float alpha = __builtin_amdgcn_exp2f(m_r[qt] - m_new);
#pragma unroll
                    for (int m = 0; m < 4; ++m)
#pragma unroll
                        for (int r = 0; r < 4; ++r) o[qt][m][r] *= alpha;
                    l_p[qt] *= alpha;
                    m_r[qt] = m_new;
                }
            }
#pragma unroll
            for (int qt = 0; qt < 2; ++qt) {
                float ps = 0.f;
                union { uint32_t u[4]; f16x8 v; } bb;
#pragma unroll
                for (int t = 0; t < 2; ++t)
#pragma unroll
                    for (int pr = 0; pr < 2; ++pr) {
                        float e0 = __builtin_amdgcn_exp2f(st[qt][t][2 * pr] - m_r[qt]);
                        float e1 = __builtin_amdgcn_exp2f(st[qt][t][2 * pr + 1] - m_r[qt]);
                        ps += e0 + e1;
                        auto hp = __builtin_amdgcn_cvt_pkrtz(e0, e1);
                        bb.u[t * 2 + pr] = __builtin_bit_cast(uint32_t, hp);
                    }
                l_p[qt] += ps;
                pf[qt] = bb.v;
            }
        }

        // load V(tt) (consumed by PV in NEXT iteration — full-iter latency cover)
        vv[0] = *(const f16x8*)(vp);
        vv[1] = *(const f16x8*)(vp + 512);
        vv[2] = *(const f16x8*)(vp + 1024);
        vv[3] = *(const f16x8*)(vp + 1536);
        vp += 2048;
    }

    // ---- epilogue: PV(63) ----
#pragma unroll
    for (int qt = 0; qt < 2; ++qt) {
        o[qt][0] = MFMA(vv[0], pf[qt], o[qt][0]);
        o[qt][1] = MFMA(vv[1], pf[qt], o[qt][1]);
        o[qt][2] = MFMA(vv[2], pf[qt], o[qt][2]);
        o[qt][3] = MFMA(vv[3], pf[qt], o[qt][3]);
    }

    // normalize + store (reduce per-lane l partials: only cross-lane ops here)
#pragma unroll
    for (int qt = 0; qt < 2; ++qt) {
        float l = l_p[qt];
        l += __shfl_xor(l, 16, 64);
        l += __shfl_xor(l, 32, 64);
        float inv = 1.f / l;
        size_t cb = ((size_t)b * 2048 + qw + qt * 16 + lr) * 1024 + h * 64 + lg * 4;
#pragma unroll
        for (int m = 0; m < 4; ++m) {
            f16x4 ov;
#pragma unroll
            for (int r = 0; r < 4; ++r) ov[r] = (f16)(o[qt][m][r] * inv);
            *(f16x4*)&cat[cb + m * 16] = ov;
        }
    }
}

// ---------------------------------------------------------------------------
extern "C" void kernel_launch(void* const* d_in, const int* in_sizes, int n_in,
                              void* d_out, int out_size, void* d_ws, size_t ws_size,
                              hipStream_t stream) {
    const float* Q  = (const float*)d_in[0];
    const float* K  = (const float*)d_in[1];
    const float* V  = (const float*)d_in[2];
    const float* Wq = (const float*)d_in[3];
    const float* bq = (const float*)d_in[4];
    const float* Wk = (const float*)d_in[5];
    const float* bk = (const float*)d_in[6];
    const float* Wv = (const float*)d_in[7];
    const float* bv = (const float*)d_in[8];
    const float* Wo = (const float*)d_in[9];
    const float* bo = (const float*)d_in[10];

    char* ws = (char*)d_ws;
    size_t off = 0;
    auto alloc = [&](size_t bytes) {
        char* p = ws + off;
        off += (bytes + 255) & ~(size_t)255;
        return p;
    };
    f16* Qh  = (f16*)alloc(8192ULL * 1024 * 2);
    f16* Kh  = (f16*)alloc(8192ULL * 1024 * 2);
    f16* Vh  = (f16*)alloc(8192ULL * 1024 * 2);
    f16* WT  = (f16*)alloc(3ULL * 1024 * 1024 * 2);   // WqT|WkT|WvT contiguous
    f16* WoT = (f16*)alloc(1024ULL * 1024 * 2);
    f16* qb  = (f16*)alloc(8192ULL * 1024 * 2);   // head-major [(b,h)][s][64]
    f16* kb2 = (f16*)alloc(8192ULL * 1024 * 2);   // [bh][tile][h][p][32] permuted
    f16* vb2 = (f16*)alloc(8192ULL * 1024 * 2);   // [bh][tile][vd][32]
    f16* cat = (f16*)alloc(8192ULL * 1024 * 2);   // [B*S][H*VS]

    k_convert3<<<6144, 256, 0, stream>>>(Q, K, V, Qh, Kh, Vh);
    k_transpose_all<<<1024, 256, 0, stream>>>(Wq, Wk, Wv, Wo, WT, WoT);

    const float SC = 0.125f * 1.44269504089f;   // 1/sqrt(64) * log2(e), folded into q
    k_gemm_qkv<<<dim3(64, 24), 256, 0, stream>>>(Qh, Kh, Vh, WT, bq, bk, bv,
                                                 qb, kb2, vb2, SC);

    k_attn<<<1024, 256, 0, stream>>>(qb, kb2, vb2, cat);

    k_gemm_out<<<dim3(64, 8), 256, 0, stream>>>(cat, WoT, bo, (float*)d_out);
}

// Round 11
// 202.675 us; speedup vs baseline: 1.6826x; 1.1985x over previous
//
#include <hip/hip_runtime.h>
#include <hip/hip_fp16.h>
#include <cstdint>
#include <cstddef>

typedef _Float16 f16;
typedef _Float16 f16x8 __attribute__((ext_vector_type(8)));
typedef _Float16 f16x4 __attribute__((ext_vector_type(4)));
typedef float    f32x4 __attribute__((ext_vector_type(4)));

#define MFMA(a, b, c) __builtin_amdgcn_mfma_f32_16x16x32_f16(a, b, c, 0, 0, 0)

// B=4, S=2048, D=1024, H=16, KS=VS=64, O=1024.

__device__ __forceinline__ void gload_lds16(const f16* g, f16* l) {
    __builtin_amdgcn_global_load_lds(
        (const __attribute__((address_space(1))) void*)g,
        (__attribute__((address_space(3))) void*)l, 16, 0, 0);
}

// ------------------- fp32 -> fp16 convert (Q,K,V fused) ----------------------
__global__ void k_convert3(const float* __restrict__ Q, const float* __restrict__ K,
                           const float* __restrict__ V, f16* __restrict__ Qh,
                           f16* __restrict__ Kh, f16* __restrict__ Vh) {
    const int seg = blockIdx.x >> 11;              // 0..2 (2048 blocks each)
    const int lb  = blockIdx.x & 2047;
    const float* src = seg == 0 ? Q : (seg == 1 ? K : V);
    f16* dst = seg == 0 ? Qh : (seg == 1 ? Kh : Vh);
    int i = lb * blockDim.x + threadIdx.x;
    for (; i < 2097152; i += 524288) {             // n4 = 8192*1024/4
        float4 v = ((const float4*)src)[i];
        f16x4 h;
        h[0] = (f16)v.x; h[1] = (f16)v.y; h[2] = (f16)v.z; h[3] = (f16)v.w;
        ((f16x4*)dst)[i] = h;
    }
}

// ---------------- weight transpose + convert to fp16 (all 4 fused) ----------
// widx 0,1,2: W[H=16][D=1024][KS=64] -> WT + widx*1M, rows n=h*64+ks, cols d
// widx 3:     Wo[K=1024][N=1024]     -> WoT[n][k]
__global__ void k_transpose_all(const float* __restrict__ Wq, const float* __restrict__ Wk,
                                const float* __restrict__ Wv, const float* __restrict__ Wo,
                                f16* __restrict__ WT, f16* __restrict__ WoT) {
    __shared__ float T[64][65];
    const int bx = blockIdx.x;
    const int widx = bx >> 8, sub = bx & 255;
    const int nb = sub >> 4, db = sub & 15;
    const int tid = threadIdx.x;
    const float* W = widx == 0 ? Wq : (widx == 1 ? Wk : (widx == 2 ? Wv : Wo));
    f16* Wt = (widx < 3) ? (WT + (size_t)widx * 1048576) : WoT;
    const float* src = (widx < 3) ? (W + nb * 65536 + db * 4096)
                                  : (W + db * 65536 + nb * 64);
    const int rstride = (widx < 3) ? 64 : 1024;
    {
        int nn = tid & 63, d0 = tid >> 6;
#pragma unroll
        for (int p = 0; p < 16; ++p) {
            int dd = p * 4 + d0;
            T[dd][nn] = src[dd * rstride + nn];
        }
    }
    __syncthreads();
    {
        int dd = tid & 63, n0 = tid >> 6;
#pragma unroll
        for (int p = 0; p < 16; ++p) {
            int nn = p * 4 + n0;
            Wt[(size_t)(nb * 64 + nn) * 1024 + db * 64 + dd] = (f16)T[dd][nn];
        }
    }
}

// --------------------------- fused q/k/v GEMM --------------------------------
// blockIdx.y 0..23: seg = y>>3 (0=q,1=k,2=v), col-block = y&7.
// seg 0: q head-major [(bh)][s][64], scaled by SC
// seg 1: K tile-packed PERMUTED [bh][tile][h=d>>5][p][d&31],
//        p = 16*((ks>>2)&1) + 4*(ks>>3) + (ks&3)
// seg 2: V^T tile-packed [bh][tile=s>>5][vd][s&31]
__global__ __launch_bounds__(256) void k_gemm_qkv(
    const f16* __restrict__ Qh, const f16* __restrict__ Kh, const f16* __restrict__ Vh,
    const f16* __restrict__ WT, const float* __restrict__ bq,
    const float* __restrict__ bk, const float* __restrict__ bv,
    f16* __restrict__ qout, f16* __restrict__ kout, f16* __restrict__ vout, float SC) {
    __shared__ f16 As[128 * 32];
    __shared__ f16 Bs[128 * 32];
    const int yy = blockIdx.y;
    const int seg = yy >> 3;
    const f16* A    = seg == 0 ? Qh : (seg == 1 ? Kh : Vh);
    const f16* Bt   = WT + (size_t)seg * 1048576;
    const float* bias = seg == 0 ? bq : (seg == 1 ? bk : bv);
    const float scale = seg == 0 ? SC : 1.0f;

    const int tid = threadIdx.x;
    const int wid = tid >> 6, lane = tid & 63;
    const int wr = wid >> 1, wc = wid & 1;
    const int lr = lane & 15, lg = lane >> 4;
    const int row0 = blockIdx.x * 128, col0 = (yy & 7) * 128;

    f32x4 acc[4][4];
#pragma unroll
    for (int m = 0; m < 4; ++m)
#pragma unroll
        for (int n = 0; n < 4; ++n) acc[m][n] = (f32x4){0.f, 0.f, 0.f, 0.f};

    const int c0 = tid, c1 = tid + 256;
    const int r0 = c0 >> 2, cb0 = (c0 & 3) * 8;
    const int r1 = c1 >> 2, cb1 = (c1 & 3) * 8;

    for (int k0 = 0; k0 < 1024; k0 += 32) {
        __syncthreads();
        gload_lds16(&A[(size_t)(row0 + r0) * 1024 + k0 + cb0], &As[c0 * 8]);
        gload_lds16(&Bt[(size_t)(col0 + r0) * 1024 + k0 + cb0], &Bs[c0 * 8]);
        gload_lds16(&A[(size_t)(row0 + r1) * 1024 + k0 + cb1], &As[c1 * 8]);
        gload_lds16(&Bt[(size_t)(col0 + r1) * 1024 + k0 + cb1], &Bs[c1 * 8]);
        __syncthreads();
        f16x8 af[4], bf[4];
#pragma unroll
        for (int m = 0; m < 4; ++m) af[m] = *(const f16x8*)&As[(wr * 64 + m * 16 + lr) * 32 + lg * 8];
#pragma unroll
        for (int n = 0; n < 4; ++n) bf[n] = *(const f16x8*)&Bs[(wc * 64 + n * 16 + lr) * 32 + lg * 8];
#pragma unroll
        for (int m = 0; m < 4; ++m)
#pragma unroll
            for (int n = 0; n < 4; ++n) acc[m][n] = MFMA(af[m], bf[n], acc[m][n]);
    }

#pragma unroll
    for (int m = 0; m < 4; ++m) {
#pragma unroll
        for (int n = 0; n < 4; ++n) {
            int col = col0 + wc * 64 + n * 16 + lr;
            float bv_ = bias[col];
            int rowb = row0 + wr * 64 + m * 16 + lg * 4;
            int srow = rowb & 2047;
            if (seg == 0) {
#pragma unroll
                for (int r = 0; r < 4; ++r) {
                    int row = rowb + r;
                    size_t a = ((size_t)((row >> 11) * 16 + (col >> 6)) * 2048 + (row & 2047)) * 64 + (col & 63);
                    qout[a] = (f16)((acc[m][n][r] + bv_) * scale);
                }
            } else if (seg == 1) {
                int ks5 = srow & 31;
                int p0 = ((ks5 >> 2) & 1) * 16 + (ks5 >> 3) * 4 + (ks5 & 3);
                size_t abase = (size_t)((rowb >> 11) * 16 + (col >> 6)) * 131072
                             + (size_t)(srow >> 5) * 2048 + (size_t)((col & 63) >> 5) * 1024
                             + (col & 31);
#pragma unroll
                for (int r = 0; r < 4; ++r)
                    kout[abase + (size_t)(p0 + r) * 32] = (f16)(acc[m][n][r] + bv_);
            } else {
                size_t a = (size_t)((rowb >> 11) * 16 + (col >> 6)) * 131072
                         + (size_t)(srow >> 5) * 2048 + (size_t)(col & 63) * 32 + (srow & 31);
                f16x4 ov;
#pragma unroll
                for (int r = 0; r < 4; ++r) ov[r] = (f16)(acc[m][n][r] + bv_);
                *(f16x4*)&vout[a] = ov;
            }
        }
    }
}

// ------------------------------ output GEMM ----------------------------------
__global__ __launch_bounds__(256) void k_gemm_out(const f16* __restrict__ A,
                                                  const f16* __restrict__ Bt,
                                                  const float* __restrict__ bias,
                                                  float* __restrict__ Cout) {
    __shared__ f16 As[128 * 32];
    __shared__ f16 Bs[128 * 32];
    const int tid = threadIdx.x;
    const int wid = tid >> 6, lane = tid & 63;
    const int wr = wid >> 1, wc = wid & 1;
    const int lr = lane & 15, lg = lane >> 4;
    const int row0 = blockIdx.x * 128, col0 = blockIdx.y * 128;

    f32x4 acc[4][4];
#pragma unroll
    for (int m = 0; m < 4; ++m)
#pragma unroll
        for (int n = 0; n < 4; ++n) acc[m][n] = (f32x4){0.f, 0.f, 0.f, 0.f};

    const int c0 = tid, c1 = tid + 256;
    const int r0 = c0 >> 2, cb0 = (c0 & 3) * 8;
    const int r1 = c1 >> 2, cb1 = (c1 & 3) * 8;

    for (int k0 = 0; k0 < 1024; k0 += 32) {
        __syncthreads();
        gload_lds16(&A[(size_t)(row0 + r0) * 1024 + k0 + cb0], &As[c0 * 8]);
        gload_lds16(&Bt[(size_t)(col0 + r0) * 1024 + k0 + cb0], &Bs[c0 * 8]);
        gload_lds16(&A[(size_t)(row0 + r1) * 1024 + k0 + cb1], &As[c1 * 8]);
        gload_lds16(&Bt[(size_t)(col0 + r1) * 1024 + k0 + cb1], &Bs[c1 * 8]);
        __syncthreads();
        f16x8 af[4], bf[4];
#pragma unroll
        for (int m = 0; m < 4; ++m) af[m] = *(const f16x8*)&As[(wr * 64 + m * 16 + lr) * 32 + lg * 8];
#pragma unroll
        for (int n = 0; n < 4; ++n) bf[n] = *(const f16x8*)&Bs[(wc * 64 + n * 16 + lr) * 32 + lg * 8];
#pragma unroll
        for (int m = 0; m < 4; ++m)
#pragma unroll
            for (int n = 0; n < 4; ++n) acc[m][n] = MFMA(af[m], bf[n], acc[m][n]);
    }

#pragma unroll
    for (int m = 0; m < 4; ++m) {
#pragma unroll
        for (int n = 0; n < 4; ++n) {
            int col = col0 + wc * 64 + n * 16 + lr;
            float bv = bias[col];
#pragma unroll
            for (int r = 0; r < 4; ++r) {
                int row = row0 + wr * 64 + m * 16 + lg * 4 + r;
                Cout[(size_t)row * 1024 + col] = acc[m][n][r] + bv;
            }
        }
    }
}

// ------------------------------ attention -----------------------------------
// No LDS. 512 blocks (XCD-swizzled: 8 bh x 8 q-blocks per XCD), 4 waves/block,
// *** 64 q-rows per wave (4 q-tiles) *** — halves the redundant K/V vector-
// memory traffic per unit work (round-10 diagnosis: per-CU VM-path wall from
// 4 waves re-loading identical 8KB K/V tiles; traffic 2GB -> 1GB total).
// Tile-packed permuted K/V (contiguous 1KB wave loads; S^T lands in PV B-frag
// layout). Flat single-buffer pipeline: qkt(t) -> loadK(t+1) [+sched_barrier
// pin] -> PV(t-1) -> softmax(t) -> loadV(t). ~200 VGPR, 2 waves/SIMD.
__global__ __launch_bounds__(256, 2) void k_attn(const f16* __restrict__ q,
                                                 const f16* __restrict__ k2,
                                                 const f16* __restrict__ v2,
                                                 f16* __restrict__ cat) {
    const int g = blockIdx.x;                 // 0..511
    const int xcd = g & 7, i = g >> 3;        // i: 0..63
    const int bh = xcd * 8 + (i >> 3);        // bijective: 8 bh per XCD
    const int qb = i & 7;                     // 8 q-blocks of 256 rows per bh
    const int b = bh >> 4, h = bh & 15;

    const int tid = threadIdx.x, wid = tid >> 6, lane = tid & 63;
    const int lr = lane & 15, lg = lane >> 4;
    const int qw = qb * 256 + wid * 64;       // this wave's first q-row

    const float THR = 8.0f;

    // Q fragments (hoisted; pre-scaled by 1/8*log2e in the q GEMM)
    f16x8 qf[4][2];
#pragma unroll
    for (int qt = 0; qt < 4; ++qt)
#pragma unroll
        for (int hf = 0; hf < 2; ++hf)
            qf[qt][hf] = *(const f16x8*)&q[((size_t)bh * 2048 + qw + qt * 16 + lr) * 64 + hf * 32 + lg * 8];

    const f16* kp = k2 + (size_t)bh * 131072 + lr * 32 + lg * 8;
    const f16* vp = v2 + (size_t)bh * 131072 + lr * 32 + lg * 8;

    f32x4 o[4][4];
#pragma unroll
    for (int qt = 0; qt < 4; ++qt)
#pragma unroll
        for (int m = 0; m < 4; ++m) o[qt][m] = (f32x4){0.f, 0.f, 0.f, 0.f};
    float m_r[4] = {-1.0e30f, -1.0e30f, -1.0e30f, -1.0e30f};
    float l_p[4] = {0.f, 0.f, 0.f, 0.f};

    f16x8 ka[4], vv[4], pf[4];
    f32x4 st[4][2];

    // ---- prologue: tile 0 ----
    ka[0] = *(const f16x8*)(kp);
    ka[1] = *(const f16x8*)(kp + 1024);
    ka[2] = *(const f16x8*)(kp + 512);
    ka[3] = *(const f16x8*)(kp + 1536);
    kp += 2048;

    __builtin_amdgcn_s_setprio(1);
#pragma unroll
    for (int t = 0; t < 2; ++t)
#pragma unroll
        for (int qt = 0; qt < 4; ++qt) {
            f32x4 z = (f32x4){0.f, 0.f, 0.f, 0.f};
            z = MFMA(ka[t * 2 + 0], qf[qt][0], z);
            z = MFMA(ka[t * 2 + 1], qf[qt][1], z);
            st[qt][t] = z;
        }
    __builtin_amdgcn_s_setprio(0);

    // load K(1)
    ka[0] = *(const f16x8*)(kp);
    ka[1] = *(const f16x8*)(kp + 1024);
    ka[2] = *(const f16x8*)(kp + 512);
    ka[3] = *(const f16x8*)(kp + 1536);
    kp += 2048;

    // softmax(0) -> pf (first tile: full reduce; o == 0)
    {
#pragma unroll
        for (int qt = 0; qt < 4; ++qt) {
            float a0 = fmaxf(fmaxf(st[qt][0][0], st[qt][0][1]), st[qt][0][2]);
            float b0 = fmaxf(fmaxf(st[qt][0][3], st[qt][1][0]), st[qt][1][1]);
            float c0 = fmaxf(fmaxf(st[qt][1][2], st[qt][1][3]), a0);
            float t0 = fmaxf(b0, c0);
            t0 = fmaxf(t0, __shfl_xor(t0, 16, 64));
            t0 = fmaxf(t0, __shfl_xor(t0, 32, 64));
            m_r[qt] = t0;
        }
#pragma unroll
        for (int qt = 0; qt < 4; ++qt) {
            float ps = 0.f;
            union { uint32_t u[4]; f16x8 v; } bb;
#pragma unroll
            for (int t = 0; t < 2; ++t)
#pragma unroll
                for (int pr = 0; pr < 2; ++pr) {
                    float e0 = __builtin_amdgcn_exp2f(st[qt][t][2 * pr] - m_r[qt]);
                    float e1 = __builtin_amdgcn_exp2f(st[qt][t][2 * pr + 1] - m_r[qt]);
                    ps += e0 + e1;
                    auto hp = __builtin_amdgcn_cvt_pkrtz(e0, e1);
                    bb.u[t * 2 + pr] = __builtin_bit_cast(uint32_t, hp);
                }
            l_p[qt] += ps;
            pf[qt] = bb.v;
        }
    }

    // load V(0)
    vv[0] = *(const f16x8*)(vp);
    vv[1] = *(const f16x8*)(vp + 512);
    vv[2] = *(const f16x8*)(vp + 1024);
    vv[3] = *(const f16x8*)(vp + 1536);
    vp += 2048;

    // ---- main loop: tiles 1..63 ----
    for (int tt = 1; tt < 64; ++tt) {
        // QK^T(tt) from ka = K(tt)
        __builtin_amdgcn_s_setprio(1);
#pragma unroll
        for (int t = 0; t < 2; ++t)
#pragma unroll
            for (int qt = 0; qt < 4; ++qt) {
                f32x4 z = (f32x4){0.f, 0.f, 0.f, 0.f};
                z = MFMA(ka[t * 2 + 0], qf[qt][0], z);
                z = MFMA(ka[t * 2 + 1], qf[qt][1], z);
                st[qt][t] = z;
            }
        __builtin_amdgcn_s_setprio(0);

        // prefetch K(tt+1) — pinned here so the latency hides under softmax
        // (tt=63 reads one tile past kb2 -> start of vb2, in-bounds of d_ws)
        ka[0] = *(const f16x8*)(kp);
        ka[1] = *(const f16x8*)(kp + 1024);
        ka[2] = *(const f16x8*)(kp + 512);
        ka[3] = *(const f16x8*)(kp + 1536);
        kp += 2048;
        __builtin_amdgcn_sched_barrier(0);

        // PV(tt-1): pure MFMA on prev pf/vv — issues ahead of softmax VALU
        __builtin_amdgcn_s_setprio(1);
#pragma unroll
        for (int qt = 0; qt < 4; ++qt) {
            o[qt][0] = MFMA(vv[0], pf[qt], o[qt][0]);
            o[qt][1] = MFMA(vv[1], pf[qt], o[qt][1]);
            o[qt][2] = MFMA(vv[2], pf[qt], o[qt][2]);
            o[qt][3] = MFMA(vv[3], pf[qt], o[qt][3]);
        }
        __builtin_amdgcn_s_setprio(0);

        // softmax(tt): lazy max + P pack (overwrites pf)
        {
            float lm[4];
#pragma unroll
            for (int qt = 0; qt < 4; ++qt) {
                float a0 = fmaxf(fmaxf(st[qt][0][0], st[qt][0][1]), st[qt][0][2]);
                float b0 = fmaxf(fmaxf(st[qt][0][3], st[qt][1][0]), st[qt][1][1]);
                float c0 = fmaxf(fmaxf(st[qt][1][2], st[qt][1][3]), a0);
                lm[qt] = fmaxf(b0, c0);
            }
            bool need = (lm[0] > m_r[0] + THR) || (lm[1] > m_r[1] + THR) ||
                        (lm[2] > m_r[2] + THR) || (lm[3] > m_r[3] + THR);
            if (__any(need)) {
#pragma unroll
                for (int qt = 0; qt < 4; ++qt) {
                    float t0 = lm[qt];
                    t0 = fmaxf(t0, __shfl_xor(t0, 16, 64));
                    t0 = fmaxf(t0, __shfl_xor(t0, 32, 64));
                    float m_new = fmaxf(m_r[qt], t0);
                    float alpha = __builtin_amdgcn_exp2f(m_r[qt] - m_new);
#pragma unroll
                    for (int m = 0; m < 4; ++m)
#pragma unroll
                        for (int r = 0; r < 4; ++r) o[qt][m][r] *= alpha;
                    l_p[qt] *= alpha;
                    m_r[qt] = m_new;
                }
            }
#pragma unroll
            for (int qt = 0; qt < 4; ++qt) {
                float ps = 0.f;
                union { uint32_t u[4]; f16x8 v; } bb;
#pragma unroll
                for (int t = 0; t < 2; ++t)
#pragma unroll
                    for (int pr = 0; pr < 2; ++pr) {
                        float e0 = __builtin_amdgcn_exp2f(st[qt][t][2 * pr] - m_r[qt]);
                        float e1 = __builtin_amdgcn_exp2f(st[qt][t][2 * pr + 1] - m_r[qt]);
                        ps += e0 + e1;
                        auto hp = __builtin_amdgcn_cvt_pkrtz(e0, e1);
                        bb.u[t * 2 + pr] = __builtin_bit_cast(uint32_t, hp);
                    }
                l_p[qt] += ps;
                pf[qt] = bb.v;
            }
        }

        // load V(tt) (consumed by PV next iteration — full-iter latency cover)
        vv[0] = *(const f16x8*)(vp);
        vv[1] = *(const f16x8*)(vp + 512);
        vv[2] = *(const f16x8*)(vp + 1024);
        vv[3] = *(const f16x8*)(vp + 1536);
        vp += 2048;
    }

    // ---- epilogue: PV(63) ----
#pragma unroll
    for (int qt = 0; qt < 4; ++qt) {
        o[qt][0] = MFMA(vv[0], pf[qt], o[qt][0]);
        o[qt][1] = MFMA(vv[1], pf[qt], o[qt][1]);
        o[qt][2] = MFMA(vv[2], pf[qt], o[qt][2]);
        o[qt][3] = MFMA(vv[3], pf[qt], o[qt][3]);
    }

    // normalize + store (reduce per-lane l partials; only cross-lane ops here)
#pragma unroll
    for (int qt = 0; qt < 4; ++qt) {
        float l = l_p[qt];
        l += __shfl_xor(l, 16, 64);
        l += __shfl_xor(l, 32, 64);
        float inv = 1.f / l;
        size_t cb = ((size_t)b * 2048 + qw + qt * 16 + lr) * 1024 + h * 64 + lg * 4;
#pragma unroll
        for (int m = 0; m < 4; ++m) {
            f16x4 ov;
#pragma unroll
            for (int r = 0; r < 4; ++r) ov[r] = (f16)(o[qt][m][r] * inv);
            *(f16x4*)&cat[cb + m * 16] = ov;
        }
    }
}

// ---------------------------------------------------------------------------
extern "C" void kernel_launch(void* const* d_in, const int* in_sizes, int n_in,
                              void* d_out, int out_size, void* d_ws, size_t ws_size,
                              hipStream_t stream) {
    const float* Q  = (const float*)d_in[0];
    const float* K  = (const float*)d_in[1];
    const float* V  = (const float*)d_in[2];
    const float* Wq = (const float*)d_in[3];
    const float* bq = (const float*)d_in[4];
    const float* Wk = (const float*)d_in[5];
    const float* bk = (const float*)d_in[6];
    const float* Wv = (const float*)d_in[7];
    const float* bv = (const float*)d_in[8];
    const float* Wo = (const float*)d_in[9];
    const float* bo = (const float*)d_in[10];

    char* ws = (char*)d_ws;
    size_t off = 0;
    auto alloc = [&](size_t bytes) {
        char* p = ws + off;
        off += (bytes + 255) & ~(size_t)255;
        return p;
    };
    f16* Qh  = (f16*)alloc(8192ULL * 1024 * 2);
    f16* Kh  = (f16*)alloc(8192ULL * 1024 * 2);
    f16* Vh  = (f16*)alloc(8192ULL * 1024 * 2);
    f16* WT  = (f16*)alloc(3ULL * 1024 * 1024 * 2);   // WqT|WkT|WvT contiguous
    f16* WoT = (f16*)alloc(1024ULL * 1024 * 2);
    f16* qb  = (f16*)alloc(8192ULL * 1024 * 2);   // head-major [(b,h)][s][64]
    f16* kb2 = (f16*)alloc(8192ULL * 1024 * 2);   // [bh][tile][h][p][32] permuted
    f16* vb2 = (f16*)alloc(8192ULL * 1024 * 2);   // [bh][tile][vd][32]
    f16* cat = (f16*)alloc(8192ULL * 1024 * 2);   // [B*S][H*VS]

    k_convert3<<<6144, 256, 0, stream>>>(Q, K, V, Qh, Kh, Vh);
    k_transpose_all<<<1024, 256, 0, stream>>>(Wq, Wk, Wv, Wo, WT, WoT);

    const float SC = 0.125f * 1.44269504089f;   // 1/sqrt(64) * log2(e), folded into q
    k_gemm_qkv<<<dim3(64, 24), 256, 0, stream>>>(Qh, Kh, Vh, WT, bq, bk, bv,
                                                 qb, kb2, vb2, SC);

    k_attn<<<512, 256, 0, stream>>>(qb, kb2, vb2, cat);

    k_gemm_out<<<dim3(64, 8), 256, 0, stream>>>(cat, WoT, bo, (float*)d_out);
}